// Round 7
// baseline (481.915 us; speedup 1.0000x reference)
//
#include <hip/hip_runtime.h>

#define TT 8
#define VV 10000
#define EE 160000
#define HH 64
#define NN 16
#define CO 64
#define NOUT 224  // 160 conv outs + 64 residual
#define RR (TT * VV)

typedef float f32x4 __attribute__((ext_vector_type(4)));
typedef __bf16 bf16x8 __attribute__((ext_vector_type(8)));
typedef unsigned int uint;

#define GLOBAL_AS __attribute__((address_space(1)))
#define LDS_AS __attribute__((address_space(3)))

__device__ __forceinline__ unsigned short f2bf(float f) {
  union { float f; unsigned u; } v;
  v.f = f;
  unsigned r = v.u + 0x7fffu + ((v.u >> 16) & 1u);
  return (unsigned short)(r >> 16);
}
__device__ __forceinline__ float bf2f(unsigned h) {
  union { unsigned u; float f; } v;
  v.u = h << 16;
  return v.f;
}

__device__ __forceinline__ float wave_sum64(float v) {
#pragma unroll
  for (int m = 32; m > 0; m >>= 1) v += __shfl_xor(v, m, 64);
  return v;
}

// ==== one-kernel CSR build: per-t LDS histogram + in-block scan + scatter ====
// 8 blocks (one per timestep), 1024 threads. No global atomics.
__global__ __launch_bounds__(1024) void build_csr(const int* __restrict__ ei, int* __restrict__ off,
                                                  int* __restrict__ csr) {
  __shared__ int cnt[VV];
  __shared__ int soff[VV];
  __shared__ int tsum[1024];
  const int t = blockIdx.x;
  const int tid = threadIdx.x;
  for (int i = tid; i < VV; i += 1024) cnt[i] = 0;
  __syncthreads();
  const int* srcp = ei + (long)(t * 2) * EE;
  const int* dstp = ei + (long)(t * 2 + 1) * EE;
  for (int e = tid; e < EE; e += 1024) atomicAdd(&cnt[dstp[e]], 1);
  __syncthreads();
  // chunked exclusive scan: 10 elems/thread + 1024-wide Hillis-Steele
  int base = tid * 10;
  int vals[10];
  int s = 0;
#pragma unroll
  for (int j = 0; j < 10; j++) {
    int idx = base + j;
    int v = (idx < VV) ? cnt[idx] : 0;
    vals[j] = v;
    s += v;
  }
  __syncthreads();  // all cnt reads done
  for (int i = tid; i < VV; i += 1024) cnt[i] = 0;  // reset for pass 2
  tsum[tid] = s;
  __syncthreads();
  for (int d = 1; d < 1024; d <<= 1) {
    int x = (tid >= d) ? tsum[tid - d] : 0;
    __syncthreads();
    tsum[tid] += x;
    __syncthreads();
  }
  int ex = tsum[tid] - s;
#pragma unroll
  for (int j = 0; j < 10; j++) {
    int idx = base + j;
    if (idx < VV) soff[idx] = ex;
    ex += vals[j];
  }
  __syncthreads();
  for (int i = tid; i < VV; i += 1024) off[t * VV + i] = t * EE + soff[i];
  if (tid == 0) off[RR] = TT * EE;
  // pass 2: place edges (LDS-atomic rank + scatter)
  const int ebase = t * EE;
  for (int e = tid; e < EE; e += 1024) {
    int d = dstp[e];
    int pos = soff[d] + atomicAdd(&cnt[d], 1);
    csr[ebase + pos] = t * VV + srcp[e];
  }
}

// ---- cast xs -> A_hi[:,0:128] (bf16 hi), A_lo[:,0:128] (bf16 lo) ----
__global__ __launch_bounds__(256) void cast_x0(const float* __restrict__ xs, unsigned short* __restrict__ Ahi,
                                               unsigned short* __restrict__ Alo) {
  int idx = blockIdx.x * 256 + threadIdx.x;  // one per float4, RR*32 total
  int row = idx >> 5, c4 = (idx & 31) * 4;
  float4 v = *reinterpret_cast<const float4*>(&xs[(long)row * 128 + c4]);
  ushort4 hs, ls;
  hs.x = f2bf(v.x); hs.y = f2bf(v.y); hs.z = f2bf(v.z); hs.w = f2bf(v.w);
  ls.x = f2bf(v.x - bf2f(hs.x)); ls.y = f2bf(v.y - bf2f(hs.y));
  ls.z = f2bf(v.z - bf2f(hs.z)); ls.w = f2bf(v.w - bf2f(hs.w));
  *reinterpret_cast<ushort4*>(&Ahi[(long)row * 256 + c4]) = hs;
  *reinterpret_cast<ushort4*>(&Alo[(long)row * 128 + c4]) = ls;
}

// ---- build stacked bf16 weight matrix Bp[n][k] (transposed, row stride Ktot) + bias ----
// k regions (size Cin each): 0:hi(Wl/Wres) 1:hi(Wr/0) 2:lo(Wl/Wres) 3:lo(Wr/0) 4:hi(Wl/Wres)
__global__ __launch_bounds__(256) void prep_b(const float* __restrict__ Wl, const float* __restrict__ Wr,
                                              const float* __restrict__ Wres, const float* __restrict__ bc,
                                              const float* __restrict__ bres, int Cin, int Ktot,
                                              unsigned short* __restrict__ Bp, float* __restrict__ bias) {
  int idx = blockIdx.x * 256 + threadIdx.x;
  if (idx >= NOUT * Ktot) return;
  int n = idx / Ktot, k = idx - n * Ktot;
  int reg = k / Cin, kk = k - reg * Cin;
  float w;
  if (reg == 1 || reg == 3)
    w = (n < 160) ? Wr[kk * 160 + n] : 0.f;
  else
    w = (n < 160) ? Wl[kk * 160 + n] : Wres[kk * 64 + (n - 160)];
  unsigned short h = f2bf(w);
  Bp[idx] = (reg == 2 || reg == 3) ? f2bf(w - bf2f(h)) : h;
  if (k == 0) bias[n] = (n < 160) ? bc[n] : bres[n - 160];
}

// ---- gather layer 0 (latency-optimized): mean of bf16-hi rows, 1 wave per row ----
__global__ __launch_bounds__(256) void gather0(const int* __restrict__ off, const int* __restrict__ csr,
                                               const uint* __restrict__ Xhi, uint* __restrict__ Mout) {
  int w = threadIdx.x >> 6;
  int lane = threadIdx.x & 63;
  int row = blockIdx.x * 4 + w;
  int s = off[row], e = off[row + 1];
  float a0 = 0.f, a1 = 0.f;
  int i = s;
  for (; i + 4 <= e; i += 4) {
    int g0 = csr[i], g1 = csr[i + 1], g2 = csr[i + 2], g3 = csr[i + 3];
    uint w0 = Xhi[(long)g0 * 128 + lane];
    uint w1 = Xhi[(long)g1 * 128 + lane];
    uint w2 = Xhi[(long)g2 * 128 + lane];
    uint w3 = Xhi[(long)g3 * 128 + lane];
    a0 += bf2f(w0 & 0xffffu) + bf2f(w1 & 0xffffu) + bf2f(w2 & 0xffffu) + bf2f(w3 & 0xffffu);
    a1 += bf2f(w0 >> 16) + bf2f(w1 >> 16) + bf2f(w2 >> 16) + bf2f(w3 >> 16);
  }
  for (; i < e; i++) {
    uint w0 = Xhi[(long)csr[i] * 128 + lane];
    a0 += bf2f(w0 & 0xffffu);
    a1 += bf2f(w0 >> 16);
  }
  float inv = 1.f / (float)max(e - s, 1);
  uint hp = (uint)f2bf(a0 * inv) | ((uint)f2bf(a1 * inv) << 16);
  Mout[(long)row * 128 + 64 + lane] = hp;
}

// ---- gather layer 1: 2 rows per wave (32 lane-pairs each), mean-hi -> cols 64:128 ----
__global__ __launch_bounds__(256) void gather1(const int* __restrict__ off, const int* __restrict__ csr,
                                               const uint* __restrict__ Xhi, uint* __restrict__ Mout) {
  int w = threadIdx.x >> 6;
  int lane = threadIdx.x & 63;
  int sub = lane >> 5;
  int p = lane & 31;
  int row = blockIdx.x * 8 + w * 2 + sub;
  int s = off[row], e = off[row + 1];
  float a0 = 0.f, a1 = 0.f;
  int i = s;
  for (; i + 4 <= e; i += 4) {
    int g0 = csr[i], g1 = csr[i + 1], g2 = csr[i + 2], g3 = csr[i + 3];
    uint w0 = Xhi[(long)g0 * 128 + p];
    uint w1 = Xhi[(long)g1 * 128 + p];
    uint w2 = Xhi[(long)g2 * 128 + p];
    uint w3 = Xhi[(long)g3 * 128 + p];
    a0 += bf2f(w0 & 0xffffu) + bf2f(w1 & 0xffffu) + bf2f(w2 & 0xffffu) + bf2f(w3 & 0xffffu);
    a1 += bf2f(w0 >> 16) + bf2f(w1 >> 16) + bf2f(w2 >> 16) + bf2f(w3 >> 16);
  }
  for (; i < e; i++) {
    uint w0 = Xhi[(long)csr[i] * 128 + p];
    a0 += bf2f(w0 & 0xffffu);
    a1 += bf2f(w0 >> 16);
  }
  float inv = 1.f / (float)max(e - s, 1);
  uint hp = (uint)f2bf(a0 * inv) | ((uint)f2bf(a1 * inv) << 16);
  Mout[(long)row * 128 + 32 + p] = hp;
}

// ==== bf16x3 MFMA GEMM, 2-phase double-buffered pipeline ====
// Tile 128x224, BK=64, 8 waves (512 thr). LDS per buffer: A 16KB [128 rows x 128B]
// then B 32KB [256 rows x 128B] (rows >=224 clamped garbage). 16B-granule XOR swizzle
// (c16 ^= row&7): applied on the GLOBAL source during global_load_lds staging and on
// the ds_read address — both sides, LDS dest stays linear (m104/m231 rule).
__device__ __forceinline__ void stage_tile(char* sb, const unsigned short* aptr, long astr,
                                           const unsigned short* Bp, int Ktot, int k0, long row0,
                                           int wid, int lane) {
#pragma unroll
  for (int r = 0; r < 6; ++r) {
    int c = wid * 6 + r;  // 48 chunks of 1024B; 0-15 = A, 16-47 = B (wave-uniform)
    const char* gp;
    if (c < 16) {
      int o = c * 1024 + lane * 16;
      int arow = o >> 7;
      int ac16 = (o >> 4) & 7;
      gp = (const char*)aptr + ((row0 + arow) * astr) * 2 + ((ac16 ^ (arow & 7)) << 4);
    } else {
      int o = (c - 16) * 1024 + lane * 16;
      int brow = o >> 7;
      int bc16 = (o >> 4) & 7;
      int browc = brow < NOUT ? brow : (NOUT - 1);
      gp = (const char*)Bp + ((long)browc * Ktot + k0) * 2 + ((bc16 ^ (brow & 7)) << 4);
    }
    __builtin_amdgcn_global_load_lds((const GLOBAL_AS uint*)gp, (LDS_AS uint*)(sb + c * 1024), 16, 0, 0);
  }
}

__global__ __launch_bounds__(512) void gemm_kernel(const unsigned short* __restrict__ Ahi,
                                                   const unsigned short* __restrict__ Alo,
                                                   const unsigned short* __restrict__ Bp,
                                                   const float* __restrict__ bias, float* __restrict__ outs,
                                                   int Ktot, int sw1, int sw2, int lda, int ldalo) {
  __shared__ char sbuf[2][49152];
  const int tid = threadIdx.x;
  const long row0 = (long)blockIdx.x * 128;
  const int wid = tid >> 6, lane = tid & 63;
  const int wr = wid >> 1, wc = wid & 1;  // wave = 32 rows x 112 cols
  const int l15 = lane & 15, lg = lane >> 4;
  f32x4 acc[2][7];
#pragma unroll
  for (int i = 0; i < 2; i++)
#pragma unroll
    for (int n = 0; n < 7; n++) acc[i][n] = (f32x4)(0.f);

  const int nt = Ktot / 64;
  // region select for tile k0
  auto asel = [&](int k0, const unsigned short*& aptr, long& astr) {
    if (k0 < sw1) { aptr = Ahi + k0; astr = lda; }
    else if (k0 < sw2) { aptr = Ahi + (k0 - sw1); astr = lda; }
    else { aptr = Alo + (k0 - sw2); astr = ldalo; }
  };
  {
    const unsigned short* aptr; long astr;
    asel(0, aptr, astr);
    stage_tile(sbuf[0], aptr, astr, Bp, Ktot, 0, row0, wid, lane);
  }
  for (int kt = 0; kt < nt; ++kt) {
    const int b = kt & 1;
    if (kt + 1 < nt) {
      const unsigned short* aptr; long astr;
      asel((kt + 1) * 64, aptr, astr);
      stage_tile(sbuf[b ^ 1], aptr, astr, Bp, Ktot, (kt + 1) * 64, row0, wid, lane);
      asm volatile("s_waitcnt vmcnt(6)" ::: "memory");  // current buf's 6 loads landed
    } else {
      asm volatile("s_waitcnt vmcnt(0)" ::: "memory");
    }
    __builtin_amdgcn_s_barrier();
    __builtin_amdgcn_sched_barrier(0);
    const char* sb = sbuf[b];
#pragma unroll
    for (int kk = 0; kk < 2; ++kk) {
      const int cswz = (((kk << 2) | lg) ^ (l15 & 7)) << 4;
      bf16x8 af0 = *reinterpret_cast<const bf16x8*>(sb + (wr * 32 + l15) * 128 + cswz);
      bf16x8 af1 = *reinterpret_cast<const bf16x8*>(sb + (wr * 32 + 16 + l15) * 128 + cswz);
#pragma unroll
      for (int n = 0; n < 7; ++n) {
        bf16x8 bfr = *reinterpret_cast<const bf16x8*>(sb + 16384 + (wc * 112 + n * 16 + l15) * 128 + cswz);
        acc[0][n] = __builtin_amdgcn_mfma_f32_16x16x32_bf16(af0, bfr, acc[0][n], 0, 0, 0);
        acc[1][n] = __builtin_amdgcn_mfma_f32_16x16x32_bf16(af1, bfr, acc[1][n], 0, 0, 0);
      }
    }
    __builtin_amdgcn_sched_barrier(0);
    __builtin_amdgcn_s_barrier();  // all waves done reading buf b (next iter overwrites it)
  }
#pragma unroll
  for (int i = 0; i < 2; i++) {
    long grow = row0 + wr * 32 + i * 16 + lg * 4;
#pragma unroll
    for (int n = 0; n < 7; n++) {
      int gcol = wc * 112 + n * 16 + l15;
      float bv = bias[gcol];
#pragma unroll
      for (int r = 0; r < 4; r++) outs[(grow + r) * NOUT + gcol] = acc[i][n][r] + bv;
    }
  }
}

// ---- diagonal SSM scan over T (token-mix inlined for layer 0) ----
// outs row layout: [xh(64) | dts(64) | Bs(16) | Cs(16) | xsr(64)]
__global__ __launch_bounds__(256) void ssm_kernel(const float* __restrict__ outs, const float* __restrict__ logA,
                                                  const float* __restrict__ dlt, const float* __restrict__ tkw,
                                                  const float* __restrict__ tkb, unsigned short* __restrict__ xhi,
                                                  unsigned short* __restrict__ xlo, float* __restrict__ yfin,
                                                  int mode /*0: tkmix, write bf16 all T; 1: write last T fp32*/) {
  int v = blockIdx.x * 4 + (threadIdx.x >> 6);
  int h = threadIdx.x & 63;
  float A[NN], s[NN];
#pragma unroll
  for (int n = 0; n < NN; n++) {
    A[n] = -__expf(logA[h * NN + n]);
    s[n] = 0.f;
  }
  float dh = dlt[h];
  float w0 = 0.f, w1 = 0.f, w2 = 0.f, tb = 0.f;
  float xhm = 0.f, xh0 = 0.f;
  if (mode == 0) {
    w0 = tkw[h * 3 + 0];
    w1 = tkw[h * 3 + 1];
    w2 = tkw[h * 3 + 2];
    tb = tkb[h];
    xh0 = outs[(long)v * NOUT + h];
  }
  for (int t = 0; t < TT; t++) {
    long row = (long)t * VV + v;
    float dtr = outs[row * NOUT + HH + h] + dh;
    float dt = dtr > 20.f ? dtr : log1pf(__expf(dtr));
    float xv;
    if (mode == 0) {
      float xh1 = (t < TT - 1) ? outs[(row + VV) * NOUT + h] : 0.f;
      xv = fmaf(xhm, w0, fmaf(xh0, w1, fmaf(xh1, w2, tb)));
      xhm = xh0;
      xh0 = xh1;
    } else {
      xv = outs[row * NOUT + h];
    }
    float r = outs[row * NOUT + 160 + h];
    float y = 0.f;
#pragma unroll
    for (int n = 0; n < NN; n++) {
      float Bn = outs[row * NOUT + 2 * HH + n];
      float Cn = outs[row * NOUT + 2 * HH + NN + n];
      s[n] = fmaf(__expf(dt * A[n]), s[n], dt * Bn * xv);
      y = fmaf(s[n], Cn, y);
    }
    y = fmaxf(y, 0.f);
    float z = y + r;
    float m = wave_sum64(z) * (1.f / 64.f);
    float d = z - m;
    float var = wave_sum64(d * d) * (1.f / 64.f);
    float o = d * rsqrtf(var + 1e-5f);
    if (mode == 0) {
      unsigned short hi = f2bf(o);
      xhi[row * 256 + h] = hi;
      xlo[row * 128 + h] = f2bf(o - bf2f(hi));
    } else if (t == TT - 1) {
      yfin[(long)v * HH + h] = o;
    }
  }
}

// ---- final [V,64] @ [64,64] + b ----
__global__ __launch_bounds__(256) void final_kernel(const float* __restrict__ y, const float* __restrict__ W,
                                                    const float* __restrict__ b, float* __restrict__ out) {
  int idx = blockIdx.x * 256 + threadIdx.x;
  if (idx >= VV * CO) return;
  int j = idx & 63;
  int v = idx >> 6;
  float acc = b[j];
#pragma unroll
  for (int h = 0; h < HH; h++) acc = fmaf(y[v * HH + h], W[h * CO + j], acc);
  out[idx] = acc;
}

extern "C" void kernel_launch(void* const* d_in, const int* in_sizes, int n_in, void* d_out, int out_size,
                              void* d_ws, size_t ws_size, hipStream_t stream) {
  const float* xs = (const float*)d_in[0];
  const int* ei = (const int*)d_in[1];
  const float* Wl0 = (const float*)d_in[2];
  const float* Wr0 = (const float*)d_in[3];
  const float* bc0 = (const float*)d_in[4];
  const float* Wl1 = (const float*)d_in[5];
  const float* Wr1 = (const float*)d_in[6];
  const float* bc1 = (const float*)d_in[7];
  const float* Wres0 = (const float*)d_in[8];
  const float* bres0 = (const float*)d_in[9];
  const float* Wres1 = (const float*)d_in[10];
  const float* bres1 = (const float*)d_in[11];
  const float* tkw = (const float*)d_in[12];
  const float* tkb = (const float*)d_in[13];
  const float* logA = (const float*)d_in[14];
  const float* dlt = (const float*)d_in[15];
  const float* Wmlp = (const float*)d_in[16];
  const float* bmlp = (const float*)d_in[17];
  float* out = (float*)d_out;

  float* outs = (float*)d_ws;                          // RR*224 f32
  unsigned short* Ahi = (unsigned short*)(outs + (long)RR * NOUT);  // RR*256 bf16
  unsigned short* Alo = Ahi + (long)RR * 256;          // RR*128 bf16
  unsigned short* Bp0 = Alo + (long)RR * 128;          // 224*640
  unsigned short* Bp1 = Bp0 + 224 * 640;               // 224*320
  float* bias0 = (float*)(Bp1 + 224 * 320);            // 224
  float* bias1 = bias0 + 224;                          // 224
  float* yfin = bias1 + 224;                           // VV*64
  int* off = (int*)(yfin + (long)VV * 64);             // RR+1
  int* csr = off + RR + 1;                             // TT*EE

  // ---- CSR build: one kernel, LDS histogram + scan + scatter (no global atomics) ----
  build_csr<<<TT, 1024, 0, stream>>>(ei, off, csr);

  // ---- weight prep ----
  prep_b<<<(NOUT * 640 + 255) / 256, 256, 0, stream>>>(Wl0, Wr0, Wres0, bc0, bres0, 128, 640, Bp0, bias0);
  prep_b<<<(NOUT * 320 + 255) / 256, 256, 0, stream>>>(Wl1, Wr1, Wres1, bc1, bres1, 64, 320, Bp1, bias1);

  // ---- layer 0 ----
  cast_x0<<<RR * 32 / 256, 256, 0, stream>>>(xs, Ahi, Alo);
  gather0<<<RR / 4, 256, 0, stream>>>(off, csr, (const uint*)Ahi, (uint*)Ahi);
  gemm_kernel<<<RR / 128, 512, 0, stream>>>(Ahi, Alo, Bp0, bias0, outs, 640, 256, 512, 256, 128);
  ssm_kernel<<<VV / 4, 256, 0, stream>>>(outs, logA, dlt, tkw, tkb, Ahi, Alo, nullptr, 0);

  // ---- layer 1 ----
  gather1<<<RR / 8, 256, 0, stream>>>(off, csr, (const uint*)Ahi, (uint*)Ahi);
  gemm_kernel<<<RR / 128, 512, 0, stream>>>(Ahi, Alo, Bp1, bias1, outs, 320, 128, 256, 256, 128);
  ssm_kernel<<<VV / 4, 256, 0, stream>>>(outs, logA + HH * NN, dlt + HH, nullptr, nullptr, nullptr, nullptr, yfin, 1);

  // ---- head ----
  final_kernel<<<(VV * CO) / 256, 256, 0, stream>>>(yfin, Wmlp, bmlp, out);
}

// Round 8
// 468.278 us; speedup vs baseline: 1.0291x; 1.0291x over previous
//
#include <hip/hip_runtime.h>

#define TT 8
#define VV 10000
#define EE 160000
#define HH 64
#define NN 16
#define CO 64
#define NOUT 224  // 160 conv outs + 64 residual
#define RR (TT * VV)
#define PP 32            // partitions per timestep
#define CHUNK (EE / PP)  // 5000 edges per partition

typedef float f32x4 __attribute__((ext_vector_type(4)));
typedef __bf16 bf16x8 __attribute__((ext_vector_type(8)));
typedef unsigned int uint;

#define GLOBAL_AS __attribute__((address_space(1)))
#define LDS_AS __attribute__((address_space(3)))

__device__ __forceinline__ unsigned short f2bf(float f) {
  union { float f; unsigned u; } v;
  v.f = f;
  unsigned r = v.u + 0x7fffu + ((v.u >> 16) & 1u);
  return (unsigned short)(r >> 16);
}
__device__ __forceinline__ float bf2f(unsigned h) {
  union { unsigned u; float f; } v;
  v.u = h << 16;
  return v.f;
}

__device__ __forceinline__ float wave_sum64(float v) {
#pragma unroll
  for (int m = 32; m > 0; m >>= 1) v += __shfl_xor(v, m, 64);
  return v;
}

// ==== CSR build, hierarchical, no global atomics, 256-block saturation ====
// K1: per-(t,partition) LDS histogram -> part[block][V]
__global__ __launch_bounds__(1024) void hist_part(const int* __restrict__ ei, int* __restrict__ part) {
  __shared__ int cnt[VV];
  const int t = blockIdx.x / PP, p = blockIdx.x % PP;
  const int tid = threadIdx.x;
  for (int i = tid; i < VV; i += 1024) cnt[i] = 0;
  __syncthreads();
  const int* dstp = ei + (long)(t * 2 + 1) * EE + p * CHUNK;
  for (int e = tid; e < CHUNK; e += 1024) atomicAdd(&cnt[dstp[e]], 1);
  __syncthreads();
  int* op = part + (long)blockIdx.x * VV;
  for (int i = tid; i < VV; i += 1024) op[i] = cnt[i];
}

// K2: per-t — exclusive prefix over partitions (in-place in part) + v-scan -> off
__global__ __launch_bounds__(1024) void scan_part(int* __restrict__ part, int* __restrict__ off) {
  __shared__ int tsum[1024];
  const int t = blockIdx.x, tid = threadIdx.x;
  const int base = tid * 10;
  int vals[10];
  int s = 0;
#pragma unroll
  for (int j = 0; j < 10; j++) {
    int v = base + j;
    int tot = 0;
    if (v < VV) {
      int x[PP];
#pragma unroll
      for (int p = 0; p < PP; p++) x[p] = part[((long)(t * PP + p)) * VV + v];
#pragma unroll
      for (int p = 0; p < PP; p++) {
        int xx = x[p];
        part[((long)(t * PP + p)) * VV + v] = tot;
        tot += xx;
      }
    }
    vals[j] = tot;
    s += tot;
  }
  tsum[tid] = s;
  __syncthreads();
  for (int d = 1; d < 1024; d <<= 1) {
    int x = (tid >= d) ? tsum[tid - d] : 0;
    __syncthreads();
    tsum[tid] += x;
    __syncthreads();
  }
  int ex = tsum[tid] - s;
#pragma unroll
  for (int j = 0; j < 10; j++) {
    int v = base + j;
    if (v < VV) off[t * VV + v] = t * EE + ex;
    ex += vals[j];
  }
  if (tid == 0 && t == 0) off[RR] = TT * EE;
}

// K3: per-(t,partition) scatter with LDS-atomic local rank
__global__ __launch_bounds__(1024) void scatter_part(const int* __restrict__ ei, const int* __restrict__ off,
                                                     const int* __restrict__ part, int* __restrict__ csr) {
  __shared__ int base_s[VV];
  __shared__ int cnt[VV];
  const int t = blockIdx.x / PP, p = blockIdx.x % PP;
  const int tid = threadIdx.x;
  const int* pp = part + (long)blockIdx.x * VV;
  const int* offt = off + t * VV;
  for (int i = tid; i < VV; i += 1024) {
    base_s[i] = offt[i] + pp[i];
    cnt[i] = 0;
  }
  __syncthreads();
  const int* srcp = ei + (long)(t * 2) * EE + p * CHUNK;
  const int* dstp = ei + (long)(t * 2 + 1) * EE + p * CHUNK;
  for (int e = tid; e < CHUNK; e += 1024) {
    int d = dstp[e];
    int r = atomicAdd(&cnt[d], 1);
    csr[base_s[d] + r] = t * VV + srcp[e];
  }
}

// ---- cast xs -> A_hi[:,0:128] (bf16 hi), A_lo[:,0:128] (bf16 lo) ----
__global__ __launch_bounds__(256) void cast_x0(const float* __restrict__ xs, unsigned short* __restrict__ Ahi,
                                               unsigned short* __restrict__ Alo) {
  int idx = blockIdx.x * 256 + threadIdx.x;  // one per float4, RR*32 total
  int row = idx >> 5, c4 = (idx & 31) * 4;
  float4 v = *reinterpret_cast<const float4*>(&xs[(long)row * 128 + c4]);
  ushort4 hs, ls;
  hs.x = f2bf(v.x); hs.y = f2bf(v.y); hs.z = f2bf(v.z); hs.w = f2bf(v.w);
  ls.x = f2bf(v.x - bf2f(hs.x)); ls.y = f2bf(v.y - bf2f(hs.y));
  ls.z = f2bf(v.z - bf2f(hs.z)); ls.w = f2bf(v.w - bf2f(hs.w));
  *reinterpret_cast<ushort4*>(&Ahi[(long)row * 256 + c4]) = hs;
  *reinterpret_cast<ushort4*>(&Alo[(long)row * 128 + c4]) = ls;
}

// ---- build stacked bf16 weight matrix Bp[n][k] (transposed, row stride Ktot) + bias ----
// k regions (size Cin each): 0:hi(Wl/Wres) 1:hi(Wr/0) 2:lo(Wl/Wres) 3:lo(Wr/0) 4:hi(Wl/Wres)
__global__ __launch_bounds__(256) void prep_b(const float* __restrict__ Wl, const float* __restrict__ Wr,
                                              const float* __restrict__ Wres, const float* __restrict__ bc,
                                              const float* __restrict__ bres, int Cin, int Ktot,
                                              unsigned short* __restrict__ Bp, float* __restrict__ bias) {
  int idx = blockIdx.x * 256 + threadIdx.x;
  if (idx >= NOUT * Ktot) return;
  int n = idx / Ktot, k = idx - n * Ktot;
  int reg = k / Cin, kk = k - reg * Cin;
  float w;
  if (reg == 1 || reg == 3)
    w = (n < 160) ? Wr[kk * 160 + n] : 0.f;
  else
    w = (n < 160) ? Wl[kk * 160 + n] : Wres[kk * 64 + (n - 160)];
  unsigned short h = f2bf(w);
  Bp[idx] = (reg == 2 || reg == 3) ? f2bf(w - bf2f(h)) : h;
  if (k == 0) bias[n] = (n < 160) ? bc[n] : bres[n - 160];
}

// ---- gather layer 0 (latency-optimized): mean of bf16-hi rows, 1 wave per row ----
__global__ __launch_bounds__(256) void gather0(const int* __restrict__ off, const int* __restrict__ csr,
                                               const uint* __restrict__ Xhi, uint* __restrict__ Mout) {
  int w = threadIdx.x >> 6;
  int lane = threadIdx.x & 63;
  int row = blockIdx.x * 4 + w;
  int s = off[row], e = off[row + 1];
  float a0 = 0.f, a1 = 0.f;
  int i = s;
  for (; i + 4 <= e; i += 4) {
    int g0 = csr[i], g1 = csr[i + 1], g2 = csr[i + 2], g3 = csr[i + 3];
    uint w0 = Xhi[(long)g0 * 128 + lane];
    uint w1 = Xhi[(long)g1 * 128 + lane];
    uint w2 = Xhi[(long)g2 * 128 + lane];
    uint w3 = Xhi[(long)g3 * 128 + lane];
    a0 += bf2f(w0 & 0xffffu) + bf2f(w1 & 0xffffu) + bf2f(w2 & 0xffffu) + bf2f(w3 & 0xffffu);
    a1 += bf2f(w0 >> 16) + bf2f(w1 >> 16) + bf2f(w2 >> 16) + bf2f(w3 >> 16);
  }
  for (; i < e; i++) {
    uint w0 = Xhi[(long)csr[i] * 128 + lane];
    a0 += bf2f(w0 & 0xffffu);
    a1 += bf2f(w0 >> 16);
  }
  float inv = 1.f / (float)max(e - s, 1);
  uint hp = (uint)f2bf(a0 * inv) | ((uint)f2bf(a1 * inv) << 16);
  Mout[(long)row * 128 + 64 + lane] = hp;
}

// ---- gather layer 1: 2 rows per wave (32 lane-pairs each), mean-hi -> cols 64:128 ----
__global__ __launch_bounds__(256) void gather1(const int* __restrict__ off, const int* __restrict__ csr,
                                               const uint* __restrict__ Xhi, uint* __restrict__ Mout) {
  int w = threadIdx.x >> 6;
  int lane = threadIdx.x & 63;
  int sub = lane >> 5;
  int p = lane & 31;
  int row = blockIdx.x * 8 + w * 2 + sub;
  int s = off[row], e = off[row + 1];
  float a0 = 0.f, a1 = 0.f;
  int i = s;
  for (; i + 4 <= e; i += 4) {
    int g0 = csr[i], g1 = csr[i + 1], g2 = csr[i + 2], g3 = csr[i + 3];
    uint w0 = Xhi[(long)g0 * 128 + p];
    uint w1 = Xhi[(long)g1 * 128 + p];
    uint w2 = Xhi[(long)g2 * 128 + p];
    uint w3 = Xhi[(long)g3 * 128 + p];
    a0 += bf2f(w0 & 0xffffu) + bf2f(w1 & 0xffffu) + bf2f(w2 & 0xffffu) + bf2f(w3 & 0xffffu);
    a1 += bf2f(w0 >> 16) + bf2f(w1 >> 16) + bf2f(w2 >> 16) + bf2f(w3 >> 16);
  }
  for (; i < e; i++) {
    uint w0 = Xhi[(long)csr[i] * 128 + p];
    a0 += bf2f(w0 & 0xffffu);
    a1 += bf2f(w0 >> 16);
  }
  float inv = 1.f / (float)max(e - s, 1);
  uint hp = (uint)f2bf(a0 * inv) | ((uint)f2bf(a1 * inv) << 16);
  Mout[(long)row * 128 + 32 + p] = hp;
}

// ==== bf16x3 MFMA GEMM, 2-phase double-buffered pipeline ====
// Tile 128x224, BK=64, 8 waves (512 thr). LDS per buffer: A 16KB [128 rows x 128B]
// then B 32KB [256 rows x 128B] (rows >=224 clamped garbage). 16B-granule XOR swizzle
// (c16 ^= row&7): applied on the GLOBAL source during global_load_lds staging and on
// the ds_read address — both sides, LDS dest stays linear (m104/m231 rule).
__device__ __forceinline__ void stage_tile(char* sb, const unsigned short* aptr, long astr,
                                           const unsigned short* Bp, int Ktot, int k0, long row0,
                                           int wid, int lane) {
#pragma unroll
  for (int r = 0; r < 6; ++r) {
    int c = wid * 6 + r;  // 48 chunks of 1024B; 0-15 = A, 16-47 = B (wave-uniform)
    const char* gp;
    if (c < 16) {
      int o = c * 1024 + lane * 16;
      int arow = o >> 7;
      int ac16 = (o >> 4) & 7;
      gp = (const char*)aptr + ((row0 + arow) * astr) * 2 + ((ac16 ^ (arow & 7)) << 4);
    } else {
      int o = (c - 16) * 1024 + lane * 16;
      int brow = o >> 7;
      int bc16 = (o >> 4) & 7;
      int browc = brow < NOUT ? brow : (NOUT - 1);
      gp = (const char*)Bp + ((long)browc * Ktot + k0) * 2 + ((bc16 ^ (brow & 7)) << 4);
    }
    __builtin_amdgcn_global_load_lds((const GLOBAL_AS uint*)gp, (LDS_AS uint*)(sb + c * 1024), 16, 0, 0);
  }
}

__global__ __launch_bounds__(512) void gemm_kernel(const unsigned short* __restrict__ Ahi,
                                                   const unsigned short* __restrict__ Alo,
                                                   const unsigned short* __restrict__ Bp,
                                                   const float* __restrict__ bias, float* __restrict__ outs,
                                                   int Ktot, int sw1, int sw2, int lda, int ldalo) {
  __shared__ char sbuf[2][49152];
  const int tid = threadIdx.x;
  const long row0 = (long)blockIdx.x * 128;
  const int wid = tid >> 6, lane = tid & 63;
  const int wr = wid >> 1, wc = wid & 1;  // wave = 32 rows x 112 cols
  const int l15 = lane & 15, lg = lane >> 4;
  f32x4 acc[2][7];
#pragma unroll
  for (int i = 0; i < 2; i++)
#pragma unroll
    for (int n = 0; n < 7; n++) acc[i][n] = (f32x4)(0.f);

  const int nt = Ktot / 64;
  // region select for tile k0
  auto asel = [&](int k0, const unsigned short*& aptr, long& astr) {
    if (k0 < sw1) { aptr = Ahi + k0; astr = lda; }
    else if (k0 < sw2) { aptr = Ahi + (k0 - sw1); astr = lda; }
    else { aptr = Alo + (k0 - sw2); astr = ldalo; }
  };
  {
    const unsigned short* aptr; long astr;
    asel(0, aptr, astr);
    stage_tile(sbuf[0], aptr, astr, Bp, Ktot, 0, row0, wid, lane);
  }
  for (int kt = 0; kt < nt; ++kt) {
    const int b = kt & 1;
    if (kt + 1 < nt) {
      const unsigned short* aptr; long astr;
      asel((kt + 1) * 64, aptr, astr);
      stage_tile(sbuf[b ^ 1], aptr, astr, Bp, Ktot, (kt + 1) * 64, row0, wid, lane);
      asm volatile("s_waitcnt vmcnt(6)" ::: "memory");  // current buf's 6 loads landed
    } else {
      asm volatile("s_waitcnt vmcnt(0)" ::: "memory");
    }
    __builtin_amdgcn_s_barrier();
    __builtin_amdgcn_sched_barrier(0);
    const char* sb = sbuf[b];
#pragma unroll
    for (int kk = 0; kk < 2; ++kk) {
      const int cswz = (((kk << 2) | lg) ^ (l15 & 7)) << 4;
      bf16x8 af0 = *reinterpret_cast<const bf16x8*>(sb + (wr * 32 + l15) * 128 + cswz);
      bf16x8 af1 = *reinterpret_cast<const bf16x8*>(sb + (wr * 32 + 16 + l15) * 128 + cswz);
#pragma unroll
      for (int n = 0; n < 7; ++n) {
        bf16x8 bfr = *reinterpret_cast<const bf16x8*>(sb + 16384 + (wc * 112 + n * 16 + l15) * 128 + cswz);
        acc[0][n] = __builtin_amdgcn_mfma_f32_16x16x32_bf16(af0, bfr, acc[0][n], 0, 0, 0);
        acc[1][n] = __builtin_amdgcn_mfma_f32_16x16x32_bf16(af1, bfr, acc[1][n], 0, 0, 0);
      }
    }
    __builtin_amdgcn_sched_barrier(0);
    __builtin_amdgcn_s_barrier();  // all waves done reading buf b (next iter overwrites it)
  }
#pragma unroll
  for (int i = 0; i < 2; i++) {
    long grow = row0 + wr * 32 + i * 16 + lg * 4;
#pragma unroll
    for (int n = 0; n < 7; n++) {
      int gcol = wc * 112 + n * 16 + l15;
      float bv = bias[gcol];
#pragma unroll
      for (int r = 0; r < 4; r++) outs[(grow + r) * NOUT + gcol] = acc[i][n][r] + bv;
    }
  }
}

// ---- diagonal SSM scan over T (token-mix inlined for layer 0) ----
// outs row layout: [xh(64) | dts(64) | Bs(16) | Cs(16) | xsr(64)]
__global__ __launch_bounds__(256) void ssm_kernel(const float* __restrict__ outs, const float* __restrict__ logA,
                                                  const float* __restrict__ dlt, const float* __restrict__ tkw,
                                                  const float* __restrict__ tkb, unsigned short* __restrict__ xhi,
                                                  unsigned short* __restrict__ xlo, float* __restrict__ yfin,
                                                  int mode /*0: tkmix, write bf16 all T; 1: write last T fp32*/) {
  int v = blockIdx.x * 4 + (threadIdx.x >> 6);
  int h = threadIdx.x & 63;
  float A[NN], s[NN];
#pragma unroll
  for (int n = 0; n < NN; n++) {
    A[n] = -__expf(logA[h * NN + n]);
    s[n] = 0.f;
  }
  float dh = dlt[h];
  float w0 = 0.f, w1 = 0.f, w2 = 0.f, tb = 0.f;
  float xhm = 0.f, xh0 = 0.f;
  if (mode == 0) {
    w0 = tkw[h * 3 + 0];
    w1 = tkw[h * 3 + 1];
    w2 = tkw[h * 3 + 2];
    tb = tkb[h];
    xh0 = outs[(long)v * NOUT + h];
  }
  for (int t = 0; t < TT; t++) {
    long row = (long)t * VV + v;
    float dtr = outs[row * NOUT + HH + h] + dh;
    float dt = dtr > 20.f ? dtr : log1pf(__expf(dtr));
    float xv;
    if (mode == 0) {
      float xh1 = (t < TT - 1) ? outs[(row + VV) * NOUT + h] : 0.f;
      xv = fmaf(xhm, w0, fmaf(xh0, w1, fmaf(xh1, w2, tb)));
      xhm = xh0;
      xh0 = xh1;
    } else {
      xv = outs[row * NOUT + h];
    }
    float r = outs[row * NOUT + 160 + h];
    float y = 0.f;
#pragma unroll
    for (int n = 0; n < NN; n++) {
      float Bn = outs[row * NOUT + 2 * HH + n];
      float Cn = outs[row * NOUT + 2 * HH + NN + n];
      s[n] = fmaf(__expf(dt * A[n]), s[n], dt * Bn * xv);
      y = fmaf(s[n], Cn, y);
    }
    y = fmaxf(y, 0.f);
    float z = y + r;
    float m = wave_sum64(z) * (1.f / 64.f);
    float d = z - m;
    float var = wave_sum64(d * d) * (1.f / 64.f);
    float o = d * rsqrtf(var + 1e-5f);
    if (mode == 0) {
      unsigned short hi = f2bf(o);
      xhi[row * 256 + h] = hi;
      xlo[row * 128 + h] = f2bf(o - bf2f(hi));
    } else if (t == TT - 1) {
      yfin[(long)v * HH + h] = o;
    }
  }
}

// ---- final [V,64] @ [64,64] + b ----
__global__ __launch_bounds__(256) void final_kernel(const float* __restrict__ y, const float* __restrict__ W,
                                                    const float* __restrict__ b, float* __restrict__ out) {
  int idx = blockIdx.x * 256 + threadIdx.x;
  if (idx >= VV * CO) return;
  int j = idx & 63;
  int v = idx >> 6;
  float acc = b[j];
#pragma unroll
  for (int h = 0; h < HH; h++) acc = fmaf(y[v * HH + h], W[h * CO + j], acc);
  out[idx] = acc;
}

extern "C" void kernel_launch(void* const* d_in, const int* in_sizes, int n_in, void* d_out, int out_size,
                              void* d_ws, size_t ws_size, hipStream_t stream) {
  const float* xs = (const float*)d_in[0];
  const int* ei = (const int*)d_in[1];
  const float* Wl0 = (const float*)d_in[2];
  const float* Wr0 = (const float*)d_in[3];
  const float* bc0 = (const float*)d_in[4];
  const float* Wl1 = (const float*)d_in[5];
  const float* Wr1 = (const float*)d_in[6];
  const float* bc1 = (const float*)d_in[7];
  const float* Wres0 = (const float*)d_in[8];
  const float* bres0 = (const float*)d_in[9];
  const float* Wres1 = (const float*)d_in[10];
  const float* bres1 = (const float*)d_in[11];
  const float* tkw = (const float*)d_in[12];
  const float* tkb = (const float*)d_in[13];
  const float* logA = (const float*)d_in[14];
  const float* dlt = (const float*)d_in[15];
  const float* Wmlp = (const float*)d_in[16];
  const float* bmlp = (const float*)d_in[17];
  float* out = (float*)d_out;

  float* outs = (float*)d_ws;                          // RR*224 f32
  unsigned short* Ahi = (unsigned short*)(outs + (long)RR * NOUT);  // RR*256 bf16
  unsigned short* Alo = Ahi + (long)RR * 256;          // RR*128 bf16
  unsigned short* Bp0 = Alo + (long)RR * 128;          // 224*640
  unsigned short* Bp1 = Bp0 + 224 * 640;               // 224*320
  float* bias0 = (float*)(Bp1 + 224 * 320);            // 224
  float* bias1 = bias0 + 224;                          // 224
  float* yfin = bias1 + 224;                           // VV*64
  int* off = (int*)(yfin + (long)VV * 64);             // RR+1
  int* csr = off + RR + 1;                             // TT*EE
  // part[256][VV] aliases outs: dead before the first gemm writes outs.
  int* part = (int*)outs;

  // ---- CSR build: 3 kernels, LDS histograms, no global atomics, 256-block grids ----
  hist_part<<<TT * PP, 1024, 0, stream>>>(ei, part);
  scan_part<<<TT, 1024, 0, stream>>>(part, off);
  scatter_part<<<TT * PP, 1024, 0, stream>>>(ei, off, part, csr);

  // ---- weight prep ----
  prep_b<<<(NOUT * 640 + 255) / 256, 256, 0, stream>>>(Wl0, Wr0, Wres0, bc0, bres0, 128, 640, Bp0, bias0);
  prep_b<<<(NOUT * 320 + 255) / 256, 256, 0, stream>>>(Wl1, Wr1, Wres1, bc1, bres1, 64, 320, Bp1, bias1);

  // ---- layer 0 ----
  cast_x0<<<RR * 32 / 256, 256, 0, stream>>>(xs, Ahi, Alo);
  gather0<<<RR / 4, 256, 0, stream>>>(off, csr, (const uint*)Ahi, (uint*)Ahi);
  gemm_kernel<<<RR / 128, 512, 0, stream>>>(Ahi, Alo, Bp0, bias0, outs, 640, 256, 512, 256, 128);
  ssm_kernel<<<VV / 4, 256, 0, stream>>>(outs, logA, dlt, tkw, tkb, Ahi, Alo, nullptr, 0);

  // ---- layer 1 ----
  gather1<<<RR / 8, 256, 0, stream>>>(off, csr, (const uint*)Ahi, (uint*)Ahi);
  gemm_kernel<<<RR / 128, 512, 0, stream>>>(Ahi, Alo, Bp1, bias1, outs, 320, 128, 256, 256, 128);
  ssm_kernel<<<VV / 4, 256, 0, stream>>>(outs, logA + HH * NN, dlt + HH, nullptr, nullptr, nullptr, nullptr, yfin, 1);

  // ---- head ----
  final_kernel<<<(VV * CO) / 256, 256, 0, stream>>>(yfin, Wmlp, bmlp, out);
}

// Round 9
// 319.405 us; speedup vs baseline: 1.5088x; 1.4661x over previous
//
#include <hip/hip_runtime.h>

#define TT 8
#define VV 10000
#define EE 160000
#define HH 64
#define NN 16
#define CO 64
#define NOUT 224  // 160 conv outs + 64 residual
#define RR (TT * VV)
#define PP 32            // partitions per timestep
#define CHUNK (EE / PP)  // 5000 edges per partition

typedef float f32x4 __attribute__((ext_vector_type(4)));
typedef __bf16 bf16x8 __attribute__((ext_vector_type(8)));
typedef unsigned int uint;

#define GLOBAL_AS __attribute__((address_space(1)))
#define LDS_AS __attribute__((address_space(3)))

__device__ __forceinline__ unsigned short f2bf(float f) {
  union { float f; unsigned u; } v;
  v.f = f;
  unsigned r = v.u + 0x7fffu + ((v.u >> 16) & 1u);
  return (unsigned short)(r >> 16);
}
__device__ __forceinline__ float bf2f(unsigned h) {
  union { unsigned u; float f; } v;
  v.u = h << 16;
  return v.f;
}

__device__ __forceinline__ float wave_sum64(float v) {
#pragma unroll
  for (int m = 32; m > 0; m >>= 1) v += __shfl_xor(v, m, 64);
  return v;
}

// ==== CSR build, hierarchical, no global atomics, saturated grids ====
// K1: per-(t,partition) LDS histogram -> part[block][V]
__global__ __launch_bounds__(1024) void hist_part(const int* __restrict__ ei, int* __restrict__ part) {
  __shared__ int cnt[VV];
  const int t = blockIdx.x / PP, p = blockIdx.x % PP;
  const int tid = threadIdx.x;
  for (int i = tid; i < VV; i += 1024) cnt[i] = 0;
  __syncthreads();
  const int* dstp = ei + (long)(t * 2 + 1) * EE + p * CHUNK;
  for (int e = tid; e < CHUNK; e += 1024) atomicAdd(&cnt[dstp[e]], 1);
  __syncthreads();
  int* op = part + (long)blockIdx.x * VV;
  for (int i = tid; i < VV; i += 1024) op[i] = cnt[i];
}

// K2: one thread per (t,v): exclusive prefix over the 32 partitions + total -> cnt
__global__ __launch_bounds__(256) void part_prefix(int* __restrict__ part, int* __restrict__ cnt) {
  int idx = blockIdx.x * 256 + threadIdx.x;  // t*VV + v
  if (idx >= RR) return;
  int t = idx / VV, v = idx - t * VV;
  long base = ((long)t * PP) * VV + v;
  int x[PP];
#pragma unroll
  for (int p = 0; p < PP; p++) x[p] = part[base + (long)p * VV];
  int s = 0;
#pragma unroll
  for (int p = 0; p < PP; p++) {
    int xx = x[p];
    part[base + (long)p * VV] = s;
    s += xx;
  }
  cnt[idx] = s;
}

// K3-5: global exclusive scan of cnt (RR elems). Per-t totals are exactly EE, so
// the global prefix == t*EE + within-t prefix — no per-t handling needed.
__global__ __launch_bounds__(256) void scan_block(const int* __restrict__ cnt, int* __restrict__ off,
                                                  int* __restrict__ bsum) {
  __shared__ int sm[256];
  int i = blockIdx.x * 256 + threadIdx.x;
  int v = (i < RR) ? cnt[i] : 0;
  sm[threadIdx.x] = v;
  __syncthreads();
  for (int d = 1; d < 256; d <<= 1) {
    int t = (threadIdx.x >= d) ? sm[threadIdx.x - d] : 0;
    __syncthreads();
    sm[threadIdx.x] += t;
    __syncthreads();
  }
  if (i < RR) off[i] = sm[threadIdx.x] - v;
  if (threadIdx.x == 255) bsum[blockIdx.x] = sm[255];
}

__global__ __launch_bounds__(512) void scan_tops(int* __restrict__ bsum, int nb) {
  __shared__ int sm[512];
  int v = (threadIdx.x < nb) ? bsum[threadIdx.x] : 0;
  sm[threadIdx.x] = v;
  __syncthreads();
  for (int d = 1; d < 512; d <<= 1) {
    int t = (threadIdx.x >= d) ? sm[threadIdx.x - d] : 0;
    __syncthreads();
    sm[threadIdx.x] += t;
    __syncthreads();
  }
  if (threadIdx.x < nb) bsum[threadIdx.x] = sm[threadIdx.x] - v;
}

__global__ __launch_bounds__(256) void scan_add(int* __restrict__ off, const int* __restrict__ bsum) {
  int i = blockIdx.x * 256 + threadIdx.x;
  if (i < RR) off[i] += bsum[blockIdx.x];
  if (i == 0) off[RR] = TT * EE;
}

// K6: per-(t,partition) scatter with LDS-atomic local rank
__global__ __launch_bounds__(1024) void scatter_part(const int* __restrict__ ei, const int* __restrict__ off,
                                                     const int* __restrict__ part, int* __restrict__ csr) {
  __shared__ int base_s[VV];
  __shared__ int cnt[VV];
  const int t = blockIdx.x / PP, p = blockIdx.x % PP;
  const int tid = threadIdx.x;
  const int* pp = part + (long)blockIdx.x * VV;
  const int* offt = off + t * VV;
  for (int i = tid; i < VV; i += 1024) {
    base_s[i] = offt[i] + pp[i];
    cnt[i] = 0;
  }
  __syncthreads();
  const int* srcp = ei + (long)(t * 2) * EE + p * CHUNK;
  const int* dstp = ei + (long)(t * 2 + 1) * EE + p * CHUNK;
  for (int e = tid; e < CHUNK; e += 1024) {
    int d = dstp[e];
    int r = atomicAdd(&cnt[d], 1);
    csr[base_s[d] + r] = t * VV + srcp[e];
  }
}

// ---- cast xs -> A_hi[:,0:128] (bf16 hi), A_lo[:,0:128] (bf16 lo) ----
__global__ __launch_bounds__(256) void cast_x0(const float* __restrict__ xs, unsigned short* __restrict__ Ahi,
                                               unsigned short* __restrict__ Alo) {
  int idx = blockIdx.x * 256 + threadIdx.x;  // one per float4, RR*32 total
  int row = idx >> 5, c4 = (idx & 31) * 4;
  float4 v = *reinterpret_cast<const float4*>(&xs[(long)row * 128 + c4]);
  ushort4 hs, ls;
  hs.x = f2bf(v.x); hs.y = f2bf(v.y); hs.z = f2bf(v.z); hs.w = f2bf(v.w);
  ls.x = f2bf(v.x - bf2f(hs.x)); ls.y = f2bf(v.y - bf2f(hs.y));
  ls.z = f2bf(v.z - bf2f(hs.z)); ls.w = f2bf(v.w - bf2f(hs.w));
  *reinterpret_cast<ushort4*>(&Ahi[(long)row * 256 + c4]) = hs;
  *reinterpret_cast<ushort4*>(&Alo[(long)row * 128 + c4]) = ls;
}

// ---- build stacked bf16 weight matrix Bp[n][k] (transposed, row stride Ktot) + bias ----
// k regions (size Cin each): 0:hi(Wl/Wres) 1:hi(Wr/0) 2:lo(Wl/Wres) 3:lo(Wr/0) 4:hi(Wl/Wres)
__global__ __launch_bounds__(256) void prep_b(const float* __restrict__ Wl, const float* __restrict__ Wr,
                                              const float* __restrict__ Wres, const float* __restrict__ bc,
                                              const float* __restrict__ bres, int Cin, int Ktot,
                                              unsigned short* __restrict__ Bp, float* __restrict__ bias) {
  int idx = blockIdx.x * 256 + threadIdx.x;
  if (idx >= NOUT * Ktot) return;
  int n = idx / Ktot, k = idx - n * Ktot;
  int reg = k / Cin, kk = k - reg * Cin;
  float w;
  if (reg == 1 || reg == 3)
    w = (n < 160) ? Wr[kk * 160 + n] : 0.f;
  else
    w = (n < 160) ? Wl[kk * 160 + n] : Wres[kk * 64 + (n - 160)];
  unsigned short h = f2bf(w);
  Bp[idx] = (reg == 2 || reg == 3) ? f2bf(w - bf2f(h)) : h;
  if (k == 0) bias[n] = (n < 160) ? bc[n] : bres[n - 160];
}

// ---- gather layer 0 (latency-optimized): mean of bf16-hi rows, 1 wave per row ----
__global__ __launch_bounds__(256) void gather0(const int* __restrict__ off, const int* __restrict__ csr,
                                               const uint* __restrict__ Xhi, uint* __restrict__ Mout) {
  int w = threadIdx.x >> 6;
  int lane = threadIdx.x & 63;
  int row = blockIdx.x * 4 + w;
  int s = off[row], e = off[row + 1];
  float a0 = 0.f, a1 = 0.f;
  int i = s;
  for (; i + 4 <= e; i += 4) {
    int g0 = csr[i], g1 = csr[i + 1], g2 = csr[i + 2], g3 = csr[i + 3];
    uint w0 = Xhi[(long)g0 * 128 + lane];
    uint w1 = Xhi[(long)g1 * 128 + lane];
    uint w2 = Xhi[(long)g2 * 128 + lane];
    uint w3 = Xhi[(long)g3 * 128 + lane];
    a0 += bf2f(w0 & 0xffffu) + bf2f(w1 & 0xffffu) + bf2f(w2 & 0xffffu) + bf2f(w3 & 0xffffu);
    a1 += bf2f(w0 >> 16) + bf2f(w1 >> 16) + bf2f(w2 >> 16) + bf2f(w3 >> 16);
  }
  for (; i < e; i++) {
    uint w0 = Xhi[(long)csr[i] * 128 + lane];
    a0 += bf2f(w0 & 0xffffu);
    a1 += bf2f(w0 >> 16);
  }
  float inv = 1.f / (float)max(e - s, 1);
  uint hp = (uint)f2bf(a0 * inv) | ((uint)f2bf(a1 * inv) << 16);
  Mout[(long)row * 128 + 64 + lane] = hp;
}

// ---- gather layer 1: 2 rows per wave (32 lane-pairs each), mean-hi -> cols 64:128 ----
__global__ __launch_bounds__(256) void gather1(const int* __restrict__ off, const int* __restrict__ csr,
                                               const uint* __restrict__ Xhi, uint* __restrict__ Mout) {
  int w = threadIdx.x >> 6;
  int lane = threadIdx.x & 63;
  int sub = lane >> 5;
  int p = lane & 31;
  int row = blockIdx.x * 8 + w * 2 + sub;
  int s = off[row], e = off[row + 1];
  float a0 = 0.f, a1 = 0.f;
  int i = s;
  for (; i + 4 <= e; i += 4) {
    int g0 = csr[i], g1 = csr[i + 1], g2 = csr[i + 2], g3 = csr[i + 3];
    uint w0 = Xhi[(long)g0 * 128 + p];
    uint w1 = Xhi[(long)g1 * 128 + p];
    uint w2 = Xhi[(long)g2 * 128 + p];
    uint w3 = Xhi[(long)g3 * 128 + p];
    a0 += bf2f(w0 & 0xffffu) + bf2f(w1 & 0xffffu) + bf2f(w2 & 0xffffu) + bf2f(w3 & 0xffffu);
    a1 += bf2f(w0 >> 16) + bf2f(w1 >> 16) + bf2f(w2 >> 16) + bf2f(w3 >> 16);
  }
  for (; i < e; i++) {
    uint w0 = Xhi[(long)csr[i] * 128 + p];
    a0 += bf2f(w0 & 0xffffu);
    a1 += bf2f(w0 >> 16);
  }
  float inv = 1.f / (float)max(e - s, 1);
  uint hp = (uint)f2bf(a0 * inv) | ((uint)f2bf(a1 * inv) << 16);
  Mout[(long)row * 128 + 32 + p] = hp;
}

// ==== bf16x3 MFMA GEMM, 2-phase double-buffered pipeline ====
// Tile 128x224, BK=64, 8 waves (512 thr). LDS per buffer: A 16KB [128 rows x 128B]
// then B 32KB [256 rows x 128B] (rows >=224 clamped garbage). 16B-granule XOR swizzle
// (c16 ^= row&7): applied on the GLOBAL source during global_load_lds staging and on
// the ds_read address — both sides, LDS dest stays linear (m104/m231 rule).
__device__ __forceinline__ void stage_tile(char* sb, const unsigned short* aptr, long astr,
                                           const unsigned short* Bp, int Ktot, int k0, long row0,
                                           int wid, int lane) {
#pragma unroll
  for (int r = 0; r < 6; ++r) {
    int c = wid * 6 + r;  // 48 chunks of 1024B; 0-15 = A, 16-47 = B (wave-uniform)
    const char* gp;
    if (c < 16) {
      int o = c * 1024 + lane * 16;
      int arow = o >> 7;
      int ac16 = (o >> 4) & 7;
      gp = (const char*)aptr + ((row0 + arow) * astr) * 2 + ((ac16 ^ (arow & 7)) << 4);
    } else {
      int o = (c - 16) * 1024 + lane * 16;
      int brow = o >> 7;
      int bc16 = (o >> 4) & 7;
      int browc = brow < NOUT ? brow : (NOUT - 1);
      gp = (const char*)Bp + ((long)browc * Ktot + k0) * 2 + ((bc16 ^ (brow & 7)) << 4);
    }
    __builtin_amdgcn_global_load_lds((const GLOBAL_AS uint*)gp, (LDS_AS uint*)(sb + c * 1024), 16, 0, 0);
  }
}

__global__ __launch_bounds__(512) void gemm_kernel(const unsigned short* __restrict__ Ahi,
                                                   const unsigned short* __restrict__ Alo,
                                                   const unsigned short* __restrict__ Bp,
                                                   const float* __restrict__ bias, float* __restrict__ outs,
                                                   int Ktot, int sw1, int sw2, int lda, int ldalo) {
  __shared__ char sbuf[2][49152];
  const int tid = threadIdx.x;
  const long row0 = (long)blockIdx.x * 128;
  const int wid = tid >> 6, lane = tid & 63;
  const int wr = wid >> 1, wc = wid & 1;  // wave = 32 rows x 112 cols
  const int l15 = lane & 15, lg = lane >> 4;
  f32x4 acc[2][7];
#pragma unroll
  for (int i = 0; i < 2; i++)
#pragma unroll
    for (int n = 0; n < 7; n++) acc[i][n] = (f32x4)(0.f);

  const int nt = Ktot / 64;
  // region select for tile k0
  auto asel = [&](int k0, const unsigned short*& aptr, long& astr) {
    if (k0 < sw1) { aptr = Ahi + k0; astr = lda; }
    else if (k0 < sw2) { aptr = Ahi + (k0 - sw1); astr = lda; }
    else { aptr = Alo + (k0 - sw2); astr = ldalo; }
  };
  {
    const unsigned short* aptr; long astr;
    asel(0, aptr, astr);
    stage_tile(sbuf[0], aptr, astr, Bp, Ktot, 0, row0, wid, lane);
  }
  for (int kt = 0; kt < nt; ++kt) {
    const int b = kt & 1;
    if (kt + 1 < nt) {
      const unsigned short* aptr; long astr;
      asel((kt + 1) * 64, aptr, astr);
      stage_tile(sbuf[b ^ 1], aptr, astr, Bp, Ktot, (kt + 1) * 64, row0, wid, lane);
      asm volatile("s_waitcnt vmcnt(6)" ::: "memory");  // current buf's 6 loads landed
    } else {
      asm volatile("s_waitcnt vmcnt(0)" ::: "memory");
    }
    __builtin_amdgcn_s_barrier();
    __builtin_amdgcn_sched_barrier(0);
    const char* sb = sbuf[b];
#pragma unroll
    for (int kk = 0; kk < 2; ++kk) {
      const int cswz = (((kk << 2) | lg) ^ (l15 & 7)) << 4;
      bf16x8 af0 = *reinterpret_cast<const bf16x8*>(sb + (wr * 32 + l15) * 128 + cswz);
      bf16x8 af1 = *reinterpret_cast<const bf16x8*>(sb + (wr * 32 + 16 + l15) * 128 + cswz);
#pragma unroll
      for (int n = 0; n < 7; ++n) {
        bf16x8 bfr = *reinterpret_cast<const bf16x8*>(sb + 16384 + (wc * 112 + n * 16 + l15) * 128 + cswz);
        acc[0][n] = __builtin_amdgcn_mfma_f32_16x16x32_bf16(af0, bfr, acc[0][n], 0, 0, 0);
        acc[1][n] = __builtin_amdgcn_mfma_f32_16x16x32_bf16(af1, bfr, acc[1][n], 0, 0, 0);
      }
    }
    __builtin_amdgcn_sched_barrier(0);
    __builtin_amdgcn_s_barrier();  // all waves done reading buf b (next iter overwrites it)
  }
#pragma unroll
  for (int i = 0; i < 2; i++) {
    long grow = row0 + wr * 32 + i * 16 + lg * 4;
#pragma unroll
    for (int n = 0; n < 7; n++) {
      int gcol = wc * 112 + n * 16 + l15;
      float bv = bias[gcol];
#pragma unroll
      for (int r = 0; r < 4; r++) outs[(grow + r) * NOUT + gcol] = acc[i][n][r] + bv;
    }
  }
}

// ---- diagonal SSM scan over T (token-mix inlined for layer 0) ----
// outs row layout: [xh(64) | dts(64) | Bs(16) | Cs(16) | xsr(64)]
__global__ __launch_bounds__(256) void ssm_kernel(const float* __restrict__ outs, const float* __restrict__ logA,
                                                  const float* __restrict__ dlt, const float* __restrict__ tkw,
                                                  const float* __restrict__ tkb, unsigned short* __restrict__ xhi,
                                                  unsigned short* __restrict__ xlo, float* __restrict__ yfin,
                                                  int mode /*0: tkmix, write bf16 all T; 1: write last T fp32*/) {
  int v = blockIdx.x * 4 + (threadIdx.x >> 6);
  int h = threadIdx.x & 63;
  float A[NN], s[NN];
#pragma unroll
  for (int n = 0; n < NN; n++) {
    A[n] = -__expf(logA[h * NN + n]);
    s[n] = 0.f;
  }
  float dh = dlt[h];
  float w0 = 0.f, w1 = 0.f, w2 = 0.f, tb = 0.f;
  float xhm = 0.f, xh0 = 0.f;
  if (mode == 0) {
    w0 = tkw[h * 3 + 0];
    w1 = tkw[h * 3 + 1];
    w2 = tkw[h * 3 + 2];
    tb = tkb[h];
    xh0 = outs[(long)v * NOUT + h];
  }
  for (int t = 0; t < TT; t++) {
    long row = (long)t * VV + v;
    float dtr = outs[row * NOUT + HH + h] + dh;
    float dt = dtr > 20.f ? dtr : log1pf(__expf(dtr));
    float xv;
    if (mode == 0) {
      float xh1 = (t < TT - 1) ? outs[(row + VV) * NOUT + h] : 0.f;
      xv = fmaf(xhm, w0, fmaf(xh0, w1, fmaf(xh1, w2, tb)));
      xhm = xh0;
      xh0 = xh1;
    } else {
      xv = outs[row * NOUT + h];
    }
    float r = outs[row * NOUT + 160 + h];
    float y = 0.f;
#pragma unroll
    for (int n = 0; n < NN; n++) {
      float Bn = outs[row * NOUT + 2 * HH + n];
      float Cn = outs[row * NOUT + 2 * HH + NN + n];
      s[n] = fmaf(__expf(dt * A[n]), s[n], dt * Bn * xv);
      y = fmaf(s[n], Cn, y);
    }
    y = fmaxf(y, 0.f);
    float z = y + r;
    float m = wave_sum64(z) * (1.f / 64.f);
    float d = z - m;
    float var = wave_sum64(d * d) * (1.f / 64.f);
    float o = d * rsqrtf(var + 1e-5f);
    if (mode == 0) {
      unsigned short hi = f2bf(o);
      xhi[row * 256 + h] = hi;
      xlo[row * 128 + h] = f2bf(o - bf2f(hi));
    } else if (t == TT - 1) {
      yfin[(long)v * HH + h] = o;
    }
  }
}

// ---- final [V,64] @ [64,64] + b ----
__global__ __launch_bounds__(256) void final_kernel(const float* __restrict__ y, const float* __restrict__ W,
                                                    const float* __restrict__ b, float* __restrict__ out) {
  int idx = blockIdx.x * 256 + threadIdx.x;
  if (idx >= VV * CO) return;
  int j = idx & 63;
  int v = idx >> 6;
  float acc = b[j];
#pragma unroll
  for (int h = 0; h < HH; h++) acc = fmaf(y[v * HH + h], W[h * CO + j], acc);
  out[idx] = acc;
}

extern "C" void kernel_launch(void* const* d_in, const int* in_sizes, int n_in, void* d_out, int out_size,
                              void* d_ws, size_t ws_size, hipStream_t stream) {
  const float* xs = (const float*)d_in[0];
  const int* ei = (const int*)d_in[1];
  const float* Wl0 = (const float*)d_in[2];
  const float* Wr0 = (const float*)d_in[3];
  const float* bc0 = (const float*)d_in[4];
  const float* Wl1 = (const float*)d_in[5];
  const float* Wr1 = (const float*)d_in[6];
  const float* bc1 = (const float*)d_in[7];
  const float* Wres0 = (const float*)d_in[8];
  const float* bres0 = (const float*)d_in[9];
  const float* Wres1 = (const float*)d_in[10];
  const float* bres1 = (const float*)d_in[11];
  const float* tkw = (const float*)d_in[12];
  const float* tkb = (const float*)d_in[13];
  const float* logA = (const float*)d_in[14];
  const float* dlt = (const float*)d_in[15];
  const float* Wmlp = (const float*)d_in[16];
  const float* bmlp = (const float*)d_in[17];
  float* out = (float*)d_out;

  float* outs = (float*)d_ws;                          // RR*224 f32
  unsigned short* Ahi = (unsigned short*)(outs + (long)RR * NOUT);  // RR*256 bf16
  unsigned short* Alo = Ahi + (long)RR * 256;          // RR*128 bf16
  unsigned short* Bp0 = Alo + (long)RR * 128;          // 224*640
  unsigned short* Bp1 = Bp0 + 224 * 640;               // 224*320
  float* bias0 = (float*)(Bp1 + 224 * 320);            // 224
  float* bias1 = bias0 + 224;                          // 224
  float* yfin = bias1 + 224;                           // VV*64
  int* off = (int*)(yfin + (long)VV * 64);             // RR+1
  int* csr = off + RR + 1;                             // TT*EE
  int* cnt = csr + TT * EE;                            // RR
  int* bsum = cnt + RR;                                // 512
  // part[256][VV] aliases outs: dead before the first gemm writes outs.
  int* part = (int*)outs;

  const int NB = (RR + 255) / 256;  // 313

  // ---- CSR build: 6 kernels, LDS histograms, no global atomics, saturated ----
  hist_part<<<TT * PP, 1024, 0, stream>>>(ei, part);
  part_prefix<<<NB, 256, 0, stream>>>(part, cnt);
  scan_block<<<NB, 256, 0, stream>>>(cnt, off, bsum);
  scan_tops<<<1, 512, 0, stream>>>(bsum, NB);
  scan_add<<<NB, 256, 0, stream>>>(off, bsum);
  scatter_part<<<TT * PP, 1024, 0, stream>>>(ei, off, part, csr);

  // ---- weight prep ----
  prep_b<<<(NOUT * 640 + 255) / 256, 256, 0, stream>>>(Wl0, Wr0, Wres0, bc0, bres0, 128, 640, Bp0, bias0);
  prep_b<<<(NOUT * 320 + 255) / 256, 256, 0, stream>>>(Wl1, Wr1, Wres1, bc1, bres1, 64, 320, Bp1, bias1);

  // ---- layer 0 ----
  cast_x0<<<RR * 32 / 256, 256, 0, stream>>>(xs, Ahi, Alo);
  gather0<<<RR / 4, 256, 0, stream>>>(off, csr, (const uint*)Ahi, (uint*)Ahi);
  gemm_kernel<<<RR / 128, 512, 0, stream>>>(Ahi, Alo, Bp0, bias0, outs, 640, 256, 512, 256, 128);
  ssm_kernel<<<VV / 4, 256, 0, stream>>>(outs, logA, dlt, tkw, tkb, Ahi, Alo, nullptr, 0);

  // ---- layer 1 ----
  gather1<<<RR / 8, 256, 0, stream>>>(off, csr, (const uint*)Ahi, (uint*)Ahi);
  gemm_kernel<<<RR / 128, 512, 0, stream>>>(Ahi, Alo, Bp1, bias1, outs, 320, 128, 256, 256, 128);
  ssm_kernel<<<VV / 4, 256, 0, stream>>>(outs, logA + HH * NN, dlt + HH, nullptr, nullptr, nullptr, nullptr, yfin, 1);

  // ---- head ----
  final_kernel<<<(VV * CO) / 256, 256, 0, stream>>>(yfin, Wmlp, bmlp, out);
}

// Round 10
// 308.339 us; speedup vs baseline: 1.5629x; 1.0359x over previous
//
#include <hip/hip_runtime.h>

#define TT 8
#define VV 10000
#define EE 160000
#define HH 64
#define NN 16
#define CO 64
#define NOUT 224  // 160 conv outs + 64 residual
#define RR (TT * VV)
#define PP 32            // partitions per timestep
#define CHUNK (EE / PP)  // 5000 edges per partition

typedef float f32x4 __attribute__((ext_vector_type(4)));
typedef __bf16 bf16x8 __attribute__((ext_vector_type(8)));
typedef unsigned int uint;

#define GLOBAL_AS __attribute__((address_space(1)))
#define LDS_AS __attribute__((address_space(3)))

__device__ __forceinline__ unsigned short f2bf(float f) {
  union { float f; unsigned u; } v;
  v.f = f;
  unsigned r = v.u + 0x7fffu + ((v.u >> 16) & 1u);
  return (unsigned short)(r >> 16);
}
__device__ __forceinline__ float bf2f(unsigned h) {
  union { unsigned u; float f; } v;
  v.u = h << 16;
  return v.f;
}

__device__ __forceinline__ float wave_sum64(float v) {
#pragma unroll
  for (int m = 32; m > 0; m >>= 1) v += __shfl_xor(v, m, 64);
  return v;
}

// ==== CSR build, hierarchical, no global atomics, saturated grids ====
// K1: per-(t,partition) LDS histogram -> part[block][V]
__global__ __launch_bounds__(1024) void hist_part(const int* __restrict__ ei, int* __restrict__ part) {
  __shared__ int cnt[VV];
  const int t = blockIdx.x / PP, p = blockIdx.x % PP;
  const int tid = threadIdx.x;
  for (int i = tid; i < VV; i += 1024) cnt[i] = 0;
  __syncthreads();
  const int* dstp = ei + (long)(t * 2 + 1) * EE + p * CHUNK;
  for (int e = tid; e < CHUNK; e += 1024) atomicAdd(&cnt[dstp[e]], 1);
  __syncthreads();
  int* op = part + (long)blockIdx.x * VV;
  for (int i = tid; i < VV; i += 1024) op[i] = cnt[i];
}

// K2: one thread per (t,v): exclusive prefix over the 32 partitions + total -> cnt
__global__ __launch_bounds__(256) void part_prefix(int* __restrict__ part, int* __restrict__ cnt) {
  int idx = blockIdx.x * 256 + threadIdx.x;  // t*VV + v
  if (idx >= RR) return;
  int t = idx / VV, v = idx - t * VV;
  long base = ((long)t * PP) * VV + v;
  int x[PP];
#pragma unroll
  for (int p = 0; p < PP; p++) x[p] = part[base + (long)p * VV];
  int s = 0;
#pragma unroll
  for (int p = 0; p < PP; p++) {
    int xx = x[p];
    part[base + (long)p * VV] = s;
    s += xx;
  }
  cnt[idx] = s;
}

// K3-5: global exclusive scan of cnt (RR elems). Per-t totals are exactly EE, so
// the global prefix == t*EE + within-t prefix — no per-t handling needed.
__global__ __launch_bounds__(256) void scan_block(const int* __restrict__ cnt, int* __restrict__ off,
                                                  int* __restrict__ bsum) {
  __shared__ int sm[256];
  int i = blockIdx.x * 256 + threadIdx.x;
  int v = (i < RR) ? cnt[i] : 0;
  sm[threadIdx.x] = v;
  __syncthreads();
  for (int d = 1; d < 256; d <<= 1) {
    int t = (threadIdx.x >= d) ? sm[threadIdx.x - d] : 0;
    __syncthreads();
    sm[threadIdx.x] += t;
    __syncthreads();
  }
  if (i < RR) off[i] = sm[threadIdx.x] - v;
  if (threadIdx.x == 255) bsum[blockIdx.x] = sm[255];
}

__global__ __launch_bounds__(512) void scan_tops(int* __restrict__ bsum, int nb) {
  __shared__ int sm[512];
  int v = (threadIdx.x < nb) ? bsum[threadIdx.x] : 0;
  sm[threadIdx.x] = v;
  __syncthreads();
  for (int d = 1; d < 512; d <<= 1) {
    int t = (threadIdx.x >= d) ? sm[threadIdx.x - d] : 0;
    __syncthreads();
    sm[threadIdx.x] += t;
    __syncthreads();
  }
  if (threadIdx.x < nb) bsum[threadIdx.x] = sm[threadIdx.x] - v;
}

__global__ __launch_bounds__(256) void scan_add(int* __restrict__ off, const int* __restrict__ bsum) {
  int i = blockIdx.x * 256 + threadIdx.x;
  if (i < RR) off[i] += bsum[blockIdx.x];
  if (i == 0) off[RR] = TT * EE;
}

// K6: per-(t,partition) scatter with LDS-atomic local rank
__global__ __launch_bounds__(1024) void scatter_part(const int* __restrict__ ei, const int* __restrict__ off,
                                                     const int* __restrict__ part, int* __restrict__ csr) {
  __shared__ int base_s[VV];
  __shared__ int cnt[VV];
  const int t = blockIdx.x / PP, p = blockIdx.x % PP;
  const int tid = threadIdx.x;
  const int* pp = part + (long)blockIdx.x * VV;
  const int* offt = off + t * VV;
  for (int i = tid; i < VV; i += 1024) {
    base_s[i] = offt[i] + pp[i];
    cnt[i] = 0;
  }
  __syncthreads();
  const int* srcp = ei + (long)(t * 2) * EE + p * CHUNK;
  const int* dstp = ei + (long)(t * 2 + 1) * EE + p * CHUNK;
  for (int e = tid; e < CHUNK; e += 1024) {
    int d = dstp[e];
    int r = atomicAdd(&cnt[d], 1);
    csr[base_s[d] + r] = t * VV + srcp[e];
  }
}

// ---- cast xs -> A_hi[:,0:128] (bf16 hi), A_lo[:,0:128] (bf16 lo) ----
__global__ __launch_bounds__(256) void cast_x0(const float* __restrict__ xs, unsigned short* __restrict__ Ahi,
                                               unsigned short* __restrict__ Alo) {
  int idx = blockIdx.x * 256 + threadIdx.x;  // one per float4, RR*32 total
  int row = idx >> 5, c4 = (idx & 31) * 4;
  float4 v = *reinterpret_cast<const float4*>(&xs[(long)row * 128 + c4]);
  ushort4 hs, ls;
  hs.x = f2bf(v.x); hs.y = f2bf(v.y); hs.z = f2bf(v.z); hs.w = f2bf(v.w);
  ls.x = f2bf(v.x - bf2f(hs.x)); ls.y = f2bf(v.y - bf2f(hs.y));
  ls.z = f2bf(v.z - bf2f(hs.z)); ls.w = f2bf(v.w - bf2f(hs.w));
  *reinterpret_cast<ushort4*>(&Ahi[(long)row * 256 + c4]) = hs;
  *reinterpret_cast<ushort4*>(&Alo[(long)row * 128 + c4]) = ls;
}

// ---- build stacked bf16 weight matrix Bp[n][k] (transposed, row stride Ktot) + bias ----
// k regions (size Cin each): 0:hi(Wl/Wres) 1:hi(Wr/0) 2:lo(Wl/Wres) 3:lo(Wr/0) 4:hi(Wl/Wres)
__global__ __launch_bounds__(256) void prep_b(const float* __restrict__ Wl, const float* __restrict__ Wr,
                                              const float* __restrict__ Wres, const float* __restrict__ bc,
                                              const float* __restrict__ bres, int Cin, int Ktot,
                                              unsigned short* __restrict__ Bp, float* __restrict__ bias) {
  int idx = blockIdx.x * 256 + threadIdx.x;
  if (idx >= NOUT * Ktot) return;
  int n = idx / Ktot, k = idx - n * Ktot;
  int reg = k / Cin, kk = k - reg * Cin;
  float w;
  if (reg == 1 || reg == 3)
    w = (n < 160) ? Wr[kk * 160 + n] : 0.f;
  else
    w = (n < 160) ? Wl[kk * 160 + n] : Wres[kk * 64 + (n - 160)];
  unsigned short h = f2bf(w);
  Bp[idx] = (reg == 2 || reg == 3) ? f2bf(w - bf2f(h)) : h;
  if (k == 0) bias[n] = (n < 160) ? bc[n] : bres[n - 160];
}

// ---- gather layer 0 (latency-optimized): mean of bf16-hi rows, 1 wave per row ----
__global__ __launch_bounds__(256) void gather0(const int* __restrict__ off, const int* __restrict__ csr,
                                               const uint* __restrict__ Xhi, uint* __restrict__ Mout) {
  int w = threadIdx.x >> 6;
  int lane = threadIdx.x & 63;
  int row = blockIdx.x * 4 + w;
  int s = off[row], e = off[row + 1];
  float a0 = 0.f, a1 = 0.f;
  int i = s;
  for (; i + 4 <= e; i += 4) {
    int g0 = csr[i], g1 = csr[i + 1], g2 = csr[i + 2], g3 = csr[i + 3];
    uint w0 = Xhi[(long)g0 * 128 + lane];
    uint w1 = Xhi[(long)g1 * 128 + lane];
    uint w2 = Xhi[(long)g2 * 128 + lane];
    uint w3 = Xhi[(long)g3 * 128 + lane];
    a0 += bf2f(w0 & 0xffffu) + bf2f(w1 & 0xffffu) + bf2f(w2 & 0xffffu) + bf2f(w3 & 0xffffu);
    a1 += bf2f(w0 >> 16) + bf2f(w1 >> 16) + bf2f(w2 >> 16) + bf2f(w3 >> 16);
  }
  for (; i < e; i++) {
    uint w0 = Xhi[(long)csr[i] * 128 + lane];
    a0 += bf2f(w0 & 0xffffu);
    a1 += bf2f(w0 >> 16);
  }
  float inv = 1.f / (float)max(e - s, 1);
  uint hp = (uint)f2bf(a0 * inv) | ((uint)f2bf(a1 * inv) << 16);
  Mout[(long)row * 128 + 64 + lane] = hp;
}

// ---- gather layer 1: 2 rows per wave (32 lane-pairs each), mean-hi -> cols 64:128 ----
__global__ __launch_bounds__(256) void gather1(const int* __restrict__ off, const int* __restrict__ csr,
                                               const uint* __restrict__ Xhi, uint* __restrict__ Mout) {
  int w = threadIdx.x >> 6;
  int lane = threadIdx.x & 63;
  int sub = lane >> 5;
  int p = lane & 31;
  int row = blockIdx.x * 8 + w * 2 + sub;
  int s = off[row], e = off[row + 1];
  float a0 = 0.f, a1 = 0.f;
  int i = s;
  for (; i + 4 <= e; i += 4) {
    int g0 = csr[i], g1 = csr[i + 1], g2 = csr[i + 2], g3 = csr[i + 3];
    uint w0 = Xhi[(long)g0 * 128 + p];
    uint w1 = Xhi[(long)g1 * 128 + p];
    uint w2 = Xhi[(long)g2 * 128 + p];
    uint w3 = Xhi[(long)g3 * 128 + p];
    a0 += bf2f(w0 & 0xffffu) + bf2f(w1 & 0xffffu) + bf2f(w2 & 0xffffu) + bf2f(w3 & 0xffffu);
    a1 += bf2f(w0 >> 16) + bf2f(w1 >> 16) + bf2f(w2 >> 16) + bf2f(w3 >> 16);
  }
  for (; i < e; i++) {
    uint w0 = Xhi[(long)csr[i] * 128 + p];
    a0 += bf2f(w0 & 0xffffu);
    a1 += bf2f(w0 >> 16);
  }
  float inv = 1.f / (float)max(e - s, 1);
  uint hp = (uint)f2bf(a0 * inv) | ((uint)f2bf(a1 * inv) << 16);
  Mout[(long)row * 128 + 32 + p] = hp;
}

// ==== bf16x3 MFMA GEMM, 2-phase double-buffered pipeline ====
// Tile 128x224, BK=64, 8 waves (512 thr). LDS per buffer: A 16KB [128 rows x 128B]
// then B 32KB [256 rows x 128B] (rows >=224 clamped garbage). 16B-granule XOR swizzle
// (c16 ^= row&7): applied on the GLOBAL source during global_load_lds staging and on
// the ds_read address — both sides, LDS dest stays linear (m104/m231 rule).
__device__ __forceinline__ void stage_tile(char* sb, const unsigned short* aptr, long astr,
                                           const unsigned short* Bp, int Ktot, int k0, long row0,
                                           int wid, int lane) {
#pragma unroll
  for (int r = 0; r < 6; ++r) {
    int c = wid * 6 + r;  // 48 chunks of 1024B; 0-15 = A, 16-47 = B (wave-uniform)
    const char* gp;
    if (c < 16) {
      int o = c * 1024 + lane * 16;
      int arow = o >> 7;
      int ac16 = (o >> 4) & 7;
      gp = (const char*)aptr + ((row0 + arow) * astr) * 2 + ((ac16 ^ (arow & 7)) << 4);
    } else {
      int o = (c - 16) * 1024 + lane * 16;
      int brow = o >> 7;
      int bc16 = (o >> 4) & 7;
      int browc = brow < NOUT ? brow : (NOUT - 1);
      gp = (const char*)Bp + ((long)browc * Ktot + k0) * 2 + ((bc16 ^ (brow & 7)) << 4);
    }
    __builtin_amdgcn_global_load_lds((const GLOBAL_AS uint*)gp, (LDS_AS uint*)(sb + c * 1024), 16, 0, 0);
  }
}

__global__ __launch_bounds__(512) void gemm_kernel(const unsigned short* __restrict__ Ahi,
                                                   const unsigned short* __restrict__ Alo,
                                                   const unsigned short* __restrict__ Bp,
                                                   const float* __restrict__ bias, float* __restrict__ outs,
                                                   int Ktot, int sw1, int sw2, int lda, int ldalo) {
  __shared__ char sbuf[2][49152];
  const int tid = threadIdx.x;
  const long row0 = (long)blockIdx.x * 128;
  const int wid = tid >> 6, lane = tid & 63;
  const int wr = wid >> 1, wc = wid & 1;  // wave = 32 rows x 112 cols
  const int l15 = lane & 15, lg = lane >> 4;
  f32x4 acc[2][7];
#pragma unroll
  for (int i = 0; i < 2; i++)
#pragma unroll
    for (int n = 0; n < 7; n++) acc[i][n] = (f32x4)(0.f);

  const int nt = Ktot / 64;
  // region select for tile k0
  auto asel = [&](int k0, const unsigned short*& aptr, long& astr) {
    if (k0 < sw1) { aptr = Ahi + k0; astr = lda; }
    else if (k0 < sw2) { aptr = Ahi + (k0 - sw1); astr = lda; }
    else { aptr = Alo + (k0 - sw2); astr = ldalo; }
  };
  {
    const unsigned short* aptr; long astr;
    asel(0, aptr, astr);
    stage_tile(sbuf[0], aptr, astr, Bp, Ktot, 0, row0, wid, lane);
  }
  for (int kt = 0; kt < nt; ++kt) {
    const int b = kt & 1;
    if (kt + 1 < nt) {
      const unsigned short* aptr; long astr;
      asel((kt + 1) * 64, aptr, astr);
      stage_tile(sbuf[b ^ 1], aptr, astr, Bp, Ktot, (kt + 1) * 64, row0, wid, lane);
      asm volatile("s_waitcnt vmcnt(6)" ::: "memory");  // current buf's 6 loads landed
    } else {
      asm volatile("s_waitcnt vmcnt(0)" ::: "memory");
    }
    __builtin_amdgcn_s_barrier();
    __builtin_amdgcn_sched_barrier(0);
    const char* sb = sbuf[b];
#pragma unroll
    for (int kk = 0; kk < 2; ++kk) {
      const int cswz = (((kk << 2) | lg) ^ (l15 & 7)) << 4;
      bf16x8 af0 = *reinterpret_cast<const bf16x8*>(sb + (wr * 32 + l15) * 128 + cswz);
      bf16x8 af1 = *reinterpret_cast<const bf16x8*>(sb + (wr * 32 + 16 + l15) * 128 + cswz);
#pragma unroll
      for (int n = 0; n < 7; ++n) {
        bf16x8 bfr = *reinterpret_cast<const bf16x8*>(sb + 16384 + (wc * 112 + n * 16 + l15) * 128 + cswz);
        acc[0][n] = __builtin_amdgcn_mfma_f32_16x16x32_bf16(af0, bfr, acc[0][n], 0, 0, 0);
        acc[1][n] = __builtin_amdgcn_mfma_f32_16x16x32_bf16(af1, bfr, acc[1][n], 0, 0, 0);
      }
    }
    __builtin_amdgcn_sched_barrier(0);
    __builtin_amdgcn_s_barrier();  // all waves done reading buf b (next iter overwrites it)
  }
#pragma unroll
  for (int i = 0; i < 2; i++) {
    long grow = row0 + wr * 32 + i * 16 + lg * 4;
#pragma unroll
    for (int n = 0; n < 7; n++) {
      int gcol = wc * 112 + n * 16 + l15;
      float bv = bias[gcol];
#pragma unroll
      for (int r = 0; r < 4; r++) outs[(grow + r) * NOUT + gcol] = acc[i][n][r] + bv;
    }
  }
}

// ---- diagonal SSM scan over T (token-mix inlined for layer 0) ----
// outs row layout: [xh(64) | dts(64) | Bs(16) | Cs(16) | xsr(64)]
// v made wave-uniform via readfirstlane so B/C loads scalarize; B/C as 8 float4 loads.
__global__ __launch_bounds__(256) void ssm_kernel(const float* __restrict__ outs, const float* __restrict__ logA,
                                                  const float* __restrict__ dlt, const float* __restrict__ tkw,
                                                  const float* __restrict__ tkb, unsigned short* __restrict__ xhi,
                                                  unsigned short* __restrict__ xlo, float* __restrict__ yfin,
                                                  int mode /*0: tkmix, write bf16 all T; 1: write last T fp32*/) {
  int wv = __builtin_amdgcn_readfirstlane(threadIdx.x) >> 6;  // wave-uniform wave id
  int v = blockIdx.x * 4 + wv;
  int h = threadIdx.x & 63;
  float A[NN], s[NN];
#pragma unroll
  for (int n = 0; n < NN; n++) {
    A[n] = -__expf(logA[h * NN + n]);
    s[n] = 0.f;
  }
  float dh = dlt[h];
  float w0 = 0.f, w1 = 0.f, w2 = 0.f, tb = 0.f;
  float xhm = 0.f, xh0 = 0.f;
  if (mode == 0) {
    w0 = tkw[h * 3 + 0];
    w1 = tkw[h * 3 + 1];
    w2 = tkw[h * 3 + 2];
    tb = tkb[h];
    xh0 = outs[(long)v * NOUT + h];
  }
  for (int t = 0; t < TT; t++) {
    const float* rp = outs + ((long)t * VV + v) * NOUT;
    float dtr = rp[HH + h] + dh;
    float dt = dtr > 20.f ? dtr : log1pf(__expf(dtr));
    float xv;
    if (mode == 0) {
      float xh1 = (t < TT - 1) ? rp[(long)VV * NOUT + h] : 0.f;
      xv = fmaf(xhm, w0, fmaf(xh0, w1, fmaf(xh1, w2, tb)));
      xhm = xh0;
      xh0 = xh1;
    } else {
      xv = rp[h];
    }
    float r = rp[160 + h];
    // B/C: wave-uniform address, 8x float4 (compiler may promote to s_load)
    const float4* bc4 = reinterpret_cast<const float4*>(rp + 2 * HH);
    float4 q0 = bc4[0], q1 = bc4[1], q2 = bc4[2], q3 = bc4[3];
    float4 q4 = bc4[4], q5 = bc4[5], q6 = bc4[6], q7 = bc4[7];
    float bb[NN] = {q0.x, q0.y, q0.z, q0.w, q1.x, q1.y, q1.z, q1.w,
                    q2.x, q2.y, q2.z, q2.w, q3.x, q3.y, q3.z, q3.w};
    float cc[NN] = {q4.x, q4.y, q4.z, q4.w, q5.x, q5.y, q5.z, q5.w,
                    q6.x, q6.y, q6.z, q6.w, q7.x, q7.y, q7.z, q7.w};
    float dtxv = dt * xv;
    float y = 0.f;
#pragma unroll
    for (int n = 0; n < NN; n++) {
      s[n] = fmaf(__expf(dt * A[n]), s[n], dtxv * bb[n]);
      y = fmaf(s[n], cc[n], y);
    }
    y = fmaxf(y, 0.f);
    float z = y + r;
    float m = wave_sum64(z) * (1.f / 64.f);
    float d = z - m;
    float var = wave_sum64(d * d) * (1.f / 64.f);
    float o = d * rsqrtf(var + 1e-5f);
    if (mode == 0) {
      long row = (long)t * VV + v;
      unsigned short hi = f2bf(o);
      xhi[row * 256 + h] = hi;
      xlo[row * 128 + h] = f2bf(o - bf2f(hi));
    } else if (t == TT - 1) {
      yfin[(long)v * HH + h] = o;
    }
  }
}

// ---- final [V,64] @ [64,64] + b ----
__global__ __launch_bounds__(256) void final_kernel(const float* __restrict__ y, const float* __restrict__ W,
                                                    const float* __restrict__ b, float* __restrict__ out) {
  int idx = blockIdx.x * 256 + threadIdx.x;
  if (idx >= VV * CO) return;
  int j = idx & 63;
  int v = idx >> 6;
  float acc = b[j];
#pragma unroll
  for (int h = 0; h < HH; h++) acc = fmaf(y[v * HH + h], W[h * CO + j], acc);
  out[idx] = acc;
}

extern "C" void kernel_launch(void* const* d_in, const int* in_sizes, int n_in, void* d_out, int out_size,
                              void* d_ws, size_t ws_size, hipStream_t stream) {
  const float* xs = (const float*)d_in[0];
  const int* ei = (const int*)d_in[1];
  const float* Wl0 = (const float*)d_in[2];
  const float* Wr0 = (const float*)d_in[3];
  const float* bc0 = (const float*)d_in[4];
  const float* Wl1 = (const float*)d_in[5];
  const float* Wr1 = (const float*)d_in[6];
  const float* bc1 = (const float*)d_in[7];
  const float* Wres0 = (const float*)d_in[8];
  const float* bres0 = (const float*)d_in[9];
  const float* Wres1 = (const float*)d_in[10];
  const float* bres1 = (const float*)d_in[11];
  const float* tkw = (const float*)d_in[12];
  const float* tkb = (const float*)d_in[13];
  const float* logA = (const float*)d_in[14];
  const float* dlt = (const float*)d_in[15];
  const float* Wmlp = (const float*)d_in[16];
  const float* bmlp = (const float*)d_in[17];
  float* out = (float*)d_out;

  float* outs = (float*)d_ws;                          // RR*224 f32
  unsigned short* Ahi = (unsigned short*)(outs + (long)RR * NOUT);  // RR*256 bf16
  unsigned short* Alo = Ahi + (long)RR * 256;          // RR*128 bf16
  unsigned short* Bp0 = Alo + (long)RR * 128;          // 224*640
  unsigned short* Bp1 = Bp0 + 224 * 640;               // 224*320
  float* bias0 = (float*)(Bp1 + 224 * 320);            // 224
  float* bias1 = bias0 + 224;                          // 224
  float* yfin = bias1 + 224;                           // VV*64
  int* off = (int*)(yfin + (long)VV * 64);             // RR+1
  int* csr = off + RR + 1;                             // TT*EE
  int* cnt = csr + TT * EE;                            // RR
  int* bsum = cnt + RR;                                // 512
  // part[256][VV] aliases outs: dead before the first gemm writes outs.
  int* part = (int*)outs;

  const int NB = (RR + 255) / 256;  // 313

  // ---- CSR build: 6 kernels, LDS histograms, no global atomics, saturated ----
  hist_part<<<TT * PP, 1024, 0, stream>>>(ei, part);
  part_prefix<<<NB, 256, 0, stream>>>(part, cnt);
  scan_block<<<NB, 256, 0, stream>>>(cnt, off, bsum);
  scan_tops<<<1, 512, 0, stream>>>(bsum, NB);
  scan_add<<<NB, 256, 0, stream>>>(off, bsum);
  scatter_part<<<TT * PP, 1024, 0, stream>>>(ei, off, part, csr);

  // ---- weight prep ----
  prep_b<<<(NOUT * 640 + 255) / 256, 256, 0, stream>>>(Wl0, Wr0, Wres0, bc0, bres0, 128, 640, Bp0, bias0);
  prep_b<<<(NOUT * 320 + 255) / 256, 256, 0, stream>>>(Wl1, Wr1, Wres1, bc1, bres1, 64, 320, Bp1, bias1);

  // ---- layer 0 ----
  cast_x0<<<RR * 32 / 256, 256, 0, stream>>>(xs, Ahi, Alo);
  gather0<<<RR / 4, 256, 0, stream>>>(off, csr, (const uint*)Ahi, (uint*)Ahi);
  gemm_kernel<<<RR / 128, 512, 0, stream>>>(Ahi, Alo, Bp0, bias0, outs, 640, 256, 512, 256, 128);
  ssm_kernel<<<VV / 4, 256, 0, stream>>>(outs, logA, dlt, tkw, tkb, Ahi, Alo, nullptr, 0);

  // ---- layer 1 ----
  gather1<<<RR / 8, 256, 0, stream>>>(off, csr, (const uint*)Ahi, (uint*)Ahi);
  gemm_kernel<<<RR / 128, 512, 0, stream>>>(Ahi, Alo, Bp1, bias1, outs, 320, 128, 256, 256, 128);
  ssm_kernel<<<VV / 4, 256, 0, stream>>>(outs, logA + HH * NN, dlt + HH, nullptr, nullptr, nullptr, nullptr, yfin, 1);

  // ---- head ----
  final_kernel<<<(VV * CO) / 256, 256, 0, stream>>>(yfin, Wmlp, bmlp, out);
}